// Round 11
// baseline (96.247 us; speedup 1.0000x reference)
//
#include <hip/hip_runtime.h>
#include <math.h>

#define BLOCK 256
#define LBv 1e-20f
#define UBv 1e20f

#if __has_builtin(__builtin_amdgcn_logf) && __has_builtin(__builtin_amdgcn_exp2f)
__device__ __forceinline__ float fast_log2(float x) { return __builtin_amdgcn_logf(x); }
__device__ __forceinline__ float fast_exp2(float x) { return __builtin_amdgcn_exp2f(x); }
#else
__device__ __forceinline__ float fast_log2(float x) { return log2f(x); }
__device__ __forceinline__ float fast_exp2(float x) { return exp2f(x); }
#endif

// ---------------- Kernel A: partial sums over a V-half ----------------
// grid: NT * SPLIT * 2 blocks; blockIdx = ((tile*SPLIT)+s)*2 + half
// each thread owns one direction, accumulates (S, Wx, Wy, Wz, Ws) over its
// V-half on RAW verts (z = v.d - m.d), writes 5 partials to ws[10][NTD].
__global__ __launch_bounds__(BLOCK) void mcnet_partial(
    const float* __restrict__ verts,   // (NT, V, 3)
    const float* __restrict__ smooth,  // (NT,)
    const float* __restrict__ dirs,    // (D, 3)
    float* __restrict__ out,           // small outputs only
    float* __restrict__ ws5,           // [10][NTD] partials
    float* __restrict__ wsM,           // [NT][3] means
    int NT, int V, int D, int SPLIT,
    size_t offMV, size_t offDIR, size_t offLV, size_t offZ)
{
    __shared__ float red[3 * BLOCK];

    const int tid  = threadIdx.x;
    const int half = blockIdx.x & 1;
    const int rest = blockIdx.x >> 1;
    const int tile = rest / SPLIT;
    const int s    = rest % SPLIT;

    const float* vp0 = verts + (size_t)tile * V * 3;

    // ---- mean over FULL V (identical in every block of this tile) ----
    float sx = 0.f, sy = 0.f, sz = 0.f;
    for (int v = tid; v < V; v += BLOCK) {
        sx += vp0[3 * v + 0]; sy += vp0[3 * v + 1]; sz += vp0[3 * v + 2];
    }
    red[tid] = sx; red[tid + BLOCK] = sy; red[tid + 2 * BLOCK] = sz;
    __syncthreads();
    for (int st = BLOCK / 2; st > 0; st >>= 1) {
        if (tid < st) {
            red[tid]             += red[tid + st];
            red[tid + BLOCK]     += red[tid + BLOCK + st];
            red[tid + 2 * BLOCK] += red[tid + 2 * BLOCK + st];
        }
        __syncthreads();
    }
    const float inv = 1.0f / (float)V;
    const float mx = red[0] * inv, my = red[BLOCK] * inv, mz = red[2 * BLOCK] * inv;

    // ---- small outputs + mean stash ----
    if (s == 0 && half == 0) {
        for (int v = tid; v < V; v += BLOCK) {
            size_t o = offLV + ((size_t)tile * V + v) * 3;
            out[o + 0] = vp0[3 * v + 0] - mx;
            out[o + 1] = vp0[3 * v + 1] - my;
            out[o + 2] = vp0[3 * v + 2] - mz;
        }
        if (tid == 0) {
            size_t mo = offMV + (size_t)tile * 3;
            out[mo + 0] = mx; out[mo + 1] = my; out[mo + 2] = mz;
            wsM[tile * 3 + 0] = mx; wsM[tile * 3 + 1] = my; wsM[tile * 3 + 2] = mz;
        }
    }
    if (blockIdx.x == 0) {
        for (int i = tid; i < D * 3; i += BLOCK)
            out[offDIR + i] = dirs[i];
        if (tid < 2) out[offZ + tid] = 0.f;
    }

    const int d = s * BLOCK + tid;
    if (d >= D) return;

    const float dx = dirs[d * 3 + 0];
    const float dy = dirs[d * 3 + 1];
    const float dz = dirs[d * 3 + 2];
    const float pv = smooth[tile];
    const float c1 = pv - 1.f;
    const float nmd = -(mx * dx + my * dy + mz * dz);

    const int v0 = half * (V >> 1);
    const int v1 = half ? V : (V >> 1);

    float S = 0.f, Wx = 0.f, Wy = 0.f, Wz = 0.f, Ws = 0.f;
    #pragma unroll 8
    for (int v = v0; v < v1; ++v) {
        float vx = vp0[3 * v + 0];
        float vy = vp0[3 * v + 1];
        float vz = vp0[3 * v + 2];
        float z  = fmaf(vx, dx, fmaf(vy, dy, fmaf(vz, dz, nmd)));
        float zc = fmaxf(z, 0.f);
        float l  = fast_log2(zc);          // -inf at 0
        float w  = fast_exp2(c1 * l);      // z^(p-1), 0 at z<=0
        S  = fmaf(w, zc, S);               // z^p accumulated
        Wx = fmaf(w, vx, Wx);
        Wy = fmaf(w, vy, Wy);
        Wz = fmaf(w, vz, Wz);
        Ws += w;
    }

    const size_t NTD = (size_t)NT * D;
    const size_t gid = (size_t)tile * D + d;
    float* base = ws5 + (size_t)half * 5 * NTD + gid;
    base[0 * NTD] = S;
    base[1 * NTD] = Wx;
    base[2 * NTD] = Wy;
    base[3 * NTD] = Wz;
    base[4 * NTD] = Ws;
}

// ---------------- Kernel B: combine halves + epilogue ----------------
__global__ __launch_bounds__(BLOCK) void mcnet_epilogue(
    const float* __restrict__ verts,
    const float* __restrict__ smooth,
    const float* __restrict__ dirs,
    float* __restrict__ out,
    const float* __restrict__ ws5,
    const float* __restrict__ wsM,
    int NT, int V, int D, size_t offDH)
{
    const size_t NTD = (size_t)NT * D;
    const size_t gid = (size_t)blockIdx.x * BLOCK + threadIdx.x;
    if (gid >= NTD) return;

    const int tile = (int)(gid / D);
    const int d    = (int)(gid - (size_t)tile * D);

    const float S  = ws5[0 * NTD + gid] + ws5[5 * NTD + gid];
    const float Wx = ws5[1 * NTD + gid] + ws5[6 * NTD + gid];
    const float Wy = ws5[2 * NTD + gid] + ws5[7 * NTD + gid];
    const float Wz = ws5[3 * NTD + gid] + ws5[8 * NTD + gid];
    const float Ws = ws5[4 * NTD + gid] + ws5[9 * NTD + gid];

    const float mx = wsM[tile * 3 + 0];
    const float my = wsM[tile * 3 + 1];
    const float mz = wsM[tile * 3 + 2];

    const float dx = dirs[d * 3 + 0];
    const float dy = dirs[d * 3 + 1];
    const float dz = dirs[d * 3 + 2];
    const float pv = smooth[tile];
    const float c1 = pv - 1.f;
    const float Sthresh = (float)V * 1e-10f;

    size_t po  = gid * 3;
    size_t dho = offDH + gid * 4;

    if (S >= Sthresh) {
        // S >= V*1e-10 => zmax^p >= 1e-10: no k-rescale, exponents bounded,
        // LB floors negligible, UB clip unreachable.
        float h = fminf(fmaxf(fast_exp2(fast_log2(S) * (1.f / pv)), LBv), UBv);
        float scale = fast_exp2(-c1 * fast_log2(h));   // h^-(p-1)
        float ax = fmaf(-mx, Ws, Wx);                  // sum w*lv
        float ay = fmaf(-my, Ws, Wy);
        float az = fmaf(-mz, Ws, Wz);
        out[po + 0] = fmaf(ax, scale, mx);
        out[po + 1] = fmaf(ay, scale, my);
        out[po + 2] = fmaf(az, scale, mz);
        out[dho + 0] = dx;
        out[dho + 1] = dy;
        out[dho + 2] = dz;
        out[dho + 3] = h;                               // k == 1
    } else {
        // ---- literal reference semantics (cold; never taken for bench data) ----
        const float* vp0 = verts + (size_t)tile * V * 3;
        float zmax = 0.f;
        for (int v = 0; v < V; ++v) {
            float z = fmaf(vp0[3 * v] - mx, dx,
                      fmaf(vp0[3 * v + 1] - my, dy, (vp0[3 * v + 2] - mz) * dz));
            zmax = fmaxf(zmax, z);
        }
        float zm_log   = (zmax > 0.f) ? log10f(zmax) : -INFINITY;
        float exponent = zm_log * pv;
        float lk = (exponent < -20.f) ? (-20.f - exponent) / pv : 0.f;
        float kk = powf(10.f, fminf(fmaxf(ceilf(lk), 0.f), UBv));

        float sum = 0.f;
        for (int v = 0; v < V; ++v) {
            float z = fmaf(vp0[3 * v] - mx, dx,
                      fmaf(vp0[3 * v + 1] - my, dy, (vp0[3 * v + 2] - mz) * dz));
            float zms = fmaxf(z, 0.f) * kk;
            float w   = (zms > 0.f) ? fminf(fmaxf(powf(zms, pv), LBv), UBv) : 0.f;
            sum += w;
        }
        float h = fminf(fmaxf(powf(sum, 1.f / pv), LBv), UBv);

        float bx = 0.f, by = 0.f, bz = 0.f;
        for (int v = 0; v < V; ++v) {
            float lx = vp0[3 * v] - mx, ly = vp0[3 * v + 1] - my, lz = vp0[3 * v + 2] - mz;
            float z     = fmaf(lx, dx, fmaf(ly, dy, lz * dz));
            float zms   = fmaxf(z, 0.f) * kk;
            float ratio = zms / h;
            float w = (ratio > 0.f) ? fminf(fmaxf(powf(ratio, c1), LBv), UBv) : LBv;
            bx = fmaf(w, lx, bx);
            by = fmaf(w, ly, by);
            bz = fmaf(w, lz, bz);
        }
        out[po + 0] = bx + mx;
        out[po + 1] = by + my;
        out[po + 2] = bz + mz;
        out[dho + 0] = dx;
        out[dho + 1] = dy;
        out[dho + 2] = dz;
        out[dho + 3] = h / kk;
    }
}

extern "C" void kernel_launch(void* const* d_in, const int* in_sizes, int n_in,
                              void* d_out, int out_size, void* d_ws, size_t ws_size,
                              hipStream_t stream) {
    const float* verts  = (const float*)d_in[0];
    const float* smooth = (const float*)d_in[1];
    const float* dirs   = (const float*)d_in[2];
    float* out = (float*)d_out;

    const int NT = in_sizes[1];
    const int D  = in_sizes[2] / 3;
    const int V  = in_sizes[0] / (3 * NT);
    const int SPLIT = (D + BLOCK - 1) / BLOCK;
    const size_t NTD = (size_t)NT * D;

    const size_t offDH  = NTD * 3;                       // after points
    const size_t offMV  = offDH  + NTD * 4;              // after direction_h
    const size_t offDIR = offMV  + (size_t)NT * 3;       // after mean_v
    const size_t offLV  = offDIR + (size_t)D * 3;        // after directions
    const size_t offZ   = offLV  + (size_t)NT * V * 3;   // after local_vertices

    float* ws5 = (float*)d_ws;            // [10][NTD]
    float* wsM = ws5 + 10 * NTD;          // [NT][3]

    dim3 block(BLOCK);
    dim3 gridA(NT * SPLIT * 2);
    hipLaunchKernelGGL(mcnet_partial, gridA, block, 0, stream,
                       verts, smooth, dirs, out, ws5, wsM,
                       NT, V, D, SPLIT, offMV, offDIR, offLV, offZ);

    dim3 gridB((unsigned)((NTD + BLOCK - 1) / BLOCK));
    hipLaunchKernelGGL(mcnet_epilogue, gridB, block, 0, stream,
                       verts, smooth, dirs, out, ws5, wsM,
                       NT, V, D, offDH);
}

// Round 12
// 92.182 us; speedup vs baseline: 1.0441x; 1.0441x over previous
//
#include <hip/hip_runtime.h>
#include <math.h>

#define BLOCK 256
#define DPB   128            // directions per block (2 threads per dir)
#define LBv 1e-20f
#define UBv 1e20f

#if __has_builtin(__builtin_amdgcn_logf) && __has_builtin(__builtin_amdgcn_exp2f)
__device__ __forceinline__ float fast_log2(float x) { return __builtin_amdgcn_logf(x); }
__device__ __forceinline__ float fast_exp2(float x) { return __builtin_amdgcn_exp2f(x); }
#else
__device__ __forceinline__ float fast_log2(float x) { return log2f(x); }
__device__ __forceinline__ float fast_exp2(float x) { return exp2f(x); }
#endif

// One block: 128 directions x 2 V-halves. Partials combined in LDS.
__global__ __launch_bounds__(BLOCK) void mcnet_vsplit(
    const float* __restrict__ verts,   // (NT, V, 3)
    const float* __restrict__ smooth,  // (NT,)
    const float* __restrict__ dirs,    // (D, 3)
    float* __restrict__ out,
    int NT, int V, int D, int SPLIT,   // SPLIT = ceil(D/DPB)
    size_t offDH, size_t offMV, size_t offDIR, size_t offLV, size_t offZ)
{
    __shared__ float red[3 * BLOCK];   // mean phase: 768 floats; combine: 640

    const int tid  = threadIdx.x;
    const int tile = blockIdx.x / SPLIT;
    const int s    = blockIdx.x % SPLIT;

    const float* vp0 = verts + (size_t)tile * V * 3;

    // ---- mean via LDS tree reduction ----
    float sx = 0.f, sy = 0.f, sz = 0.f;
    for (int v = tid; v < V; v += BLOCK) {
        sx += vp0[3 * v + 0]; sy += vp0[3 * v + 1]; sz += vp0[3 * v + 2];
    }
    red[tid] = sx; red[tid + BLOCK] = sy; red[tid + 2 * BLOCK] = sz;
    __syncthreads();
    for (int st = BLOCK / 2; st > 0; st >>= 1) {
        if (tid < st) {
            red[tid]             += red[tid + st];
            red[tid + BLOCK]     += red[tid + BLOCK + st];
            red[tid + 2 * BLOCK] += red[tid + 2 * BLOCK + st];
        }
        __syncthreads();
    }
    const float inv = 1.0f / (float)V;
    const float mx = red[0] * inv, my = red[BLOCK] * inv, mz = red[2 * BLOCK] * inv;

    // ---- small outputs ----
    if (s == 0) {
        for (int v = tid; v < V; v += BLOCK) {
            size_t o = offLV + ((size_t)tile * V + v) * 3;
            out[o + 0] = vp0[3 * v + 0] - mx;
            out[o + 1] = vp0[3 * v + 1] - my;
            out[o + 2] = vp0[3 * v + 2] - mz;
        }
        if (tid == 0) {
            size_t mo = offMV + (size_t)tile * 3;
            out[mo + 0] = mx; out[mo + 1] = my; out[mo + 2] = mz;
        }
    }
    if (blockIdx.x == 0) {
        for (int i = tid; i < D * 3; i += BLOCK)
            out[offDIR + i] = dirs[i];
        if (tid < 2) out[offZ + tid] = 0.f;
    }

    // ---- accumulate over this thread's V-half ----
    const int slot = tid & (DPB - 1);
    const int half = tid >> 7;              // 0 or 1
    const int d    = s * DPB + slot;
    const bool active = (d < D);
    const int dc   = active ? d : (D - 1);  // clamp for safe loads

    const float dx = dirs[dc * 3 + 0];
    const float dy = dirs[dc * 3 + 1];
    const float dz = dirs[dc * 3 + 2];
    const float pv = smooth[tile];
    const float c1 = pv - 1.f;
    const float nmd = -(mx * dx + my * dy + mz * dz);

    const int vh = V >> 1;
    const int v0 = half ? vh : 0;
    const int v1 = half ? V : vh;

    float S = 0.f, Wx = 0.f, Wy = 0.f, Wz = 0.f, Ws = 0.f;
    #pragma unroll 8
    for (int v = v0; v < v1; ++v) {
        float vx = vp0[3 * v + 0];
        float vy = vp0[3 * v + 1];
        float vz = vp0[3 * v + 2];
        float z  = fmaf(vx, dx, fmaf(vy, dy, fmaf(vz, dz, nmd)));
        float zc = fmaxf(z, 0.f);
        float l  = fast_log2(zc);          // -inf at 0
        float w  = fast_exp2(c1 * l);      // z^(p-1), 0 at z<=0
        S  = fmaf(w, zc, S);               // z^p accumulated
        Wx = fmaf(w, vx, Wx);
        Wy = fmaf(w, vy, Wy);
        Wz = fmaf(w, vz, Wz);
        Ws += w;
    }

    // ---- combine halves via LDS (reuse red; mean values already consumed) ----
    __syncthreads();
    if (half) {
        red[slot + 0 * DPB] = S;
        red[slot + 1 * DPB] = Wx;
        red[slot + 2 * DPB] = Wy;
        red[slot + 3 * DPB] = Wz;
        red[slot + 4 * DPB] = Ws;
    }
    __syncthreads();
    if (half || !active) return;

    S  += red[slot + 0 * DPB];
    Wx += red[slot + 1 * DPB];
    Wy += red[slot + 2 * DPB];
    Wz += red[slot + 3 * DPB];
    Ws += red[slot + 4 * DPB];

    const float Sthresh = (float)V * 1e-10f;
    size_t po  = ((size_t)tile * D + d) * 3;
    size_t dho = offDH + ((size_t)tile * D + d) * 4;

    if (S >= Sthresh) {
        // S >= V*1e-10 => zmax^p >= 1e-10: no k-rescale, exponents bounded,
        // LB floors negligible, UB clip unreachable.
        float h = fminf(fmaxf(fast_exp2(fast_log2(S) * (1.f / pv)), LBv), UBv);
        float scale = fast_exp2(-c1 * fast_log2(h));   // h^-(p-1)
        float ax = fmaf(-mx, Ws, Wx);                  // sum w*lv
        float ay = fmaf(-my, Ws, Wy);
        float az = fmaf(-mz, Ws, Wz);
        out[po + 0] = fmaf(ax, scale, mx);
        out[po + 1] = fmaf(ay, scale, my);
        out[po + 2] = fmaf(az, scale, mz);
        out[dho + 0] = dx;
        out[dho + 1] = dy;
        out[dho + 2] = dz;
        out[dho + 3] = h;                               // k == 1
    } else {
        // ---- literal reference semantics (cold; never taken for bench data) ----
        float zmax = 0.f;
        for (int v = 0; v < V; ++v) {
            float z = fmaf(vp0[3 * v] - mx, dx,
                      fmaf(vp0[3 * v + 1] - my, dy, (vp0[3 * v + 2] - mz) * dz));
            zmax = fmaxf(zmax, z);
        }
        float zm_log   = (zmax > 0.f) ? log10f(zmax) : -INFINITY;
        float exponent = zm_log * pv;
        float lk = (exponent < -20.f) ? (-20.f - exponent) / pv : 0.f;
        float kk = powf(10.f, fminf(fmaxf(ceilf(lk), 0.f), UBv));

        float sum = 0.f;
        for (int v = 0; v < V; ++v) {
            float z = fmaf(vp0[3 * v] - mx, dx,
                      fmaf(vp0[3 * v + 1] - my, dy, (vp0[3 * v + 2] - mz) * dz));
            float zms = fmaxf(z, 0.f) * kk;
            float w   = (zms > 0.f) ? fminf(fmaxf(powf(zms, pv), LBv), UBv) : 0.f;
            sum += w;
        }
        float h = fminf(fmaxf(powf(sum, 1.f / pv), LBv), UBv);

        float bx = 0.f, by = 0.f, bz = 0.f;
        for (int v = 0; v < V; ++v) {
            float lx = vp0[3 * v] - mx, ly = vp0[3 * v + 1] - my, lz = vp0[3 * v + 2] - mz;
            float z     = fmaf(lx, dx, fmaf(ly, dy, lz * dz));
            float zms   = fmaxf(z, 0.f) * kk;
            float ratio = zms / h;
            float w = (ratio > 0.f) ? fminf(fmaxf(powf(ratio, c1), LBv), UBv) : LBv;
            bx = fmaf(w, lx, bx);
            by = fmaf(w, ly, by);
            bz = fmaf(w, lz, bz);
        }
        out[po + 0] = bx + mx;
        out[po + 1] = by + my;
        out[po + 2] = bz + mz;
        out[dho + 0] = dx;
        out[dho + 1] = dy;
        out[dho + 2] = dz;
        out[dho + 3] = h / kk;
    }
}

extern "C" void kernel_launch(void* const* d_in, const int* in_sizes, int n_in,
                              void* d_out, int out_size, void* d_ws, size_t ws_size,
                              hipStream_t stream) {
    const float* verts  = (const float*)d_in[0];
    const float* smooth = (const float*)d_in[1];
    const float* dirs   = (const float*)d_in[2];
    float* out = (float*)d_out;

    const int NT = in_sizes[1];
    const int D  = in_sizes[2] / 3;
    const int V  = in_sizes[0] / (3 * NT);
    const int SPLIT = (D + DPB - 1) / DPB;               // dir-blocks per tile

    const size_t NTD = (size_t)NT * D;
    const size_t offDH  = NTD * 3;                       // after points
    const size_t offMV  = offDH  + NTD * 4;              // after direction_h
    const size_t offDIR = offMV  + (size_t)NT * 3;       // after mean_v
    const size_t offLV  = offDIR + (size_t)D * 3;        // after directions
    const size_t offZ   = offLV  + (size_t)NT * V * 3;   // after local_vertices

    dim3 grid(NT * SPLIT);
    dim3 block(BLOCK);
    hipLaunchKernelGGL(mcnet_vsplit, grid, block, 0, stream,
                       verts, smooth, dirs, out,
                       NT, V, D, SPLIT, offDH, offMV, offDIR, offLV, offZ);
}